// Round 4
// baseline (36.037 us; speedup 1.0000x reference)
//
#include <hip/hip_runtime.h>

#define HGT 100
#define WID 152
#define HW (HGT * WID)          // 15200
#define NINST 500
#define CIN 8
#define CH 8
#define NPARAMS 169
#define PPT 4                    // pixels per thread (one float4)

// param layout per instance (169 floats):
//   w0: [0,80)   (8 x 10)   w1: [80,144) (8 x 8)   w2: [144,152) (1 x 8)
//   b0: [152,160)            b1: [160,168)           b2: [168]

typedef float v2f __attribute__((ext_vector_type(2)));

// acc(v2f pair) += x(v2f VGPR pair) * w(SGPR pair, both halves equal)
static __device__ __forceinline__ void pkfma(v2f& acc, v2f x, v2f w) {
    asm("v_pk_fma_f32 %0, %1, %2, %0" : "+v"(acc) : "v"(x), "s"(w));
}

static __device__ __forceinline__ v2f pkrelu(v2f a) {
#if __has_builtin(__builtin_elementwise_max)
    v2f z = {0.0f, 0.0f};
    return __builtin_elementwise_max(a, z);
#else
    v2f r; r.x = fmaxf(a.x, 0.f); r.y = fmaxf(a.y, 0.f); return r;
#endif
}

__global__ __launch_bounds__(256, 4) void dyn_mask_head(
    const float* __restrict__ feats,   // [2, 8, HW]
    const float* __restrict__ params,  // [500, 169]
    const float* __restrict__ locs,    // [500, 2]
    const float* __restrict__ soi,     // [500]
    const int*  __restrict__ im_inds,  // [500]
    float* __restrict__ out)           // [500, HW]
{
    const int n    = blockIdx.y;                                // instance
    const int quad = blockIdx.x * blockDim.x + threadIdx.x;     // float4 index
    const int p0   = quad * PPT;                                // first pixel
    if (p0 >= HW) return;

    // wave-uniform (blockIdx.y) -> scalar loads into SGPRs
    const int   im      = im_inds[n];
    const float lx      = locs[n * 2 + 0];
    const float ly      = locs[n * 2 + 1];
    const float inv_soi = 1.0f / soi[n];
    const float* __restrict__ P = params + n * NPARAMS;

    // quad lies entirely within one row (WID % 4 == 0)
    const int py  = p0 / WID;
    const int px0 = p0 - py * WID;
    const float rely = (ly - (float)(py * 8 + 4)) * inv_soi;    // per-thread VGPR

    const float rx0 = (lx - (float)(px0 * 8 + 4)) * inv_soi;
    const float dx  = -8.0f * inv_soi;
    v2f rely2  = {rely,          rely};
    v2f relx01 = {rx0,           rx0 + dx};
    v2f relx23 = {rx0 + 2 * dx,  rx0 + 3 * dx};

    // load 8 feature channels x 4 pixels as 2 x v2f
    v2f f01[CIN], f23[CIN];
    const float* fb = feats + (size_t)im * CIN * HW + p0;
#pragma unroll
    for (int j = 0; j < CIN; ++j) {
        const float4 v = *reinterpret_cast<const float4*>(fb + (size_t)j * HW);
        v2f a = {v.x, v.y}; v2f b = {v.z, v.w};
        f01[j] = a; f23[j] = b;
    }

    // ---- layer 0: 10 -> 8, relu ----
    v2f h0a[CH], h0b[CH];
#pragma unroll
    for (int c = 0; c < CH; ++c) {
        const float b = P[152 + c];
        v2f wx = {P[c * 10 + 0], P[c * 10 + 0]};
        v2f wy = {P[c * 10 + 1], P[c * 10 + 1]};
        v2f a0 = {b, b}, a1 = {b, b};
        pkfma(a0, rely2, wy);   pkfma(a1, rely2, wy);
        pkfma(a0, relx01, wx);  pkfma(a1, relx23, wx);
#pragma unroll
        for (int i = 0; i < CIN; ++i) {
            v2f w = {P[c * 10 + 2 + i], P[c * 10 + 2 + i]};
            pkfma(a0, f01[i], w);
            pkfma(a1, f23[i], w);
        }
        h0a[c] = pkrelu(a0); h0b[c] = pkrelu(a1);
    }

    // ---- layer 1: 8 -> 8, relu ----
    v2f h1a[CH], h1b[CH];
#pragma unroll
    for (int c = 0; c < CH; ++c) {
        const float b = P[160 + c];
        v2f a0 = {b, b}, a1 = {b, b};
#pragma unroll
        for (int i = 0; i < CH; ++i) {
            v2f w = {P[80 + c * 8 + i], P[80 + c * 8 + i]};
            pkfma(a0, h0a[i], w);
            pkfma(a1, h0b[i], w);
        }
        h1a[c] = pkrelu(a0); h1b[c] = pkrelu(a1);
    }

    // ---- layer 2: 8 -> 1 ----
    const float b2 = P[168];
    v2f o0 = {b2, b2}, o1 = {b2, b2};
#pragma unroll
    for (int i = 0; i < CH; ++i) {
        v2f w = {P[144 + i], P[144 + i]};
        pkfma(o0, h1a[i], w);
        pkfma(o1, h1b[i], w);
    }

    float4 ov;
    ov.x = o0.x; ov.y = o0.y; ov.z = o1.x; ov.w = o1.y;
    *reinterpret_cast<float4*>(out + (size_t)n * HW + p0) = ov;
}

extern "C" void kernel_launch(void* const* d_in, const int* in_sizes, int n_in,
                              void* d_out, int out_size, void* d_ws, size_t ws_size,
                              hipStream_t stream) {
    const float* feats   = (const float*)d_in[0];  // mask_feats [2,8,100,152]
    const float* params  = (const float*)d_in[1];  // mask_head_params [500,169]
    const float* locs    = (const float*)d_in[2];  // instance_locations [500,2]
    const float* soi     = (const float*)d_in[3];  // soi [500]
    const int*   im_inds = (const int*)d_in[4];    // im_inds [500]
    float*       out     = (float*)d_out;          // [500,1,100,152]

    const int quads_per_inst = HW / PPT;                        // 3800
    dim3 block(256);
    dim3 grid((quads_per_inst + block.x - 1) / block.x, NINST); // (15, 500)
    dyn_mask_head<<<grid, block, 0, stream>>>(feats, params, locs, soi, im_inds, out);
}

// Round 5
// 35.139 us; speedup vs baseline: 1.0256x; 1.0256x over previous
//
#include <hip/hip_runtime.h>

#define HGT 100
#define WID 152
#define HW (HGT * WID)          // 15200
#define NINST 500
#define CIN 8
#define CH 8
#define NPARAMS 169
#define PPT 2                    // pixels per thread (one float2)

// param layout per instance (169 floats):
//   w0: [0,80)   (8 x 10)   w1: [80,144) (8 x 8)   w2: [144,152) (1 x 8)
//   b0: [152,160)            b1: [160,168)           b2: [168]

typedef float v2f __attribute__((ext_vector_type(2)));

static __device__ __forceinline__ v2f vsplat2(float x) { v2f r = {x, x}; return r; }

static __device__ __forceinline__ v2f vfma2(float w, v2f x, v2f c) {
    // uniform w folds to an SGPR operand of v_fma_f32; 2 scalar FMAs
#if __has_builtin(__builtin_elementwise_fma)
    return __builtin_elementwise_fma(vsplat2(w), x, c);
#else
    v2f r; r.x = fmaf(w, x.x, c.x); r.y = fmaf(w, x.y, c.y); return r;
#endif
}

static __device__ __forceinline__ v2f vrelu2(v2f a) {
#if __has_builtin(__builtin_elementwise_max)
    return __builtin_elementwise_max(a, vsplat2(0.0f));
#else
    v2f r; r.x = fmaxf(a.x, 0.f); r.y = fmaxf(a.y, 0.f); return r;
#endif
}

__global__ __launch_bounds__(256, 8) void dyn_mask_head(
    const float* __restrict__ feats,   // [2, 8, HW]
    const float* __restrict__ params,  // [500, 169]
    const float* __restrict__ locs,    // [500, 2]
    const float* __restrict__ soi,     // [500]
    const int*  __restrict__ im_inds,  // [500]
    float* __restrict__ out)           // [500, HW]
{
    const int n  = blockIdx.y;                                  // instance
    const int q  = blockIdx.x * blockDim.x + threadIdx.x;       // float2 index
    const int p0 = q * PPT;                                     // first pixel
    if (p0 >= HW) return;

    // wave-uniform (blockIdx.y) -> scalar loads into SGPRs
    const int   im      = im_inds[n];
    const float lx      = locs[n * 2 + 0];
    const float ly      = locs[n * 2 + 1];
    const float inv_soi = 1.0f / soi[n];
    const float* __restrict__ P = params + n * NPARAMS;

    // pair lies within one row (p0 even, WID even)
    const int py  = p0 / WID;
    const int px0 = p0 - py * WID;
    const float rely = (ly - (float)(py * 8 + 4)) * inv_soi;    // per-thread VGPR

    v2f relx;
    relx.x = (lx - (float)(px0 * 8 + 4))  * inv_soi;
    relx.y = (lx - (float)(px0 * 8 + 12)) * inv_soi;

    // load 8 feature channels x 2 pixels
    v2f f[CIN];
    const float* fb = feats + (size_t)im * CIN * HW + p0;
#pragma unroll
    for (int j = 0; j < CIN; ++j) {
        const float2 v = *reinterpret_cast<const float2*>(fb + (size_t)j * HW);
        v2f t = {v.x, v.y};
        f[j] = t;
    }

    // ---- layer 0: 10 -> 8, relu ----
    v2f h0[CH];
#pragma unroll
    for (int c = 0; c < CH; ++c) {
        const float s = fmaf(P[c * 10 + 1], rely, P[152 + c]);  // wy*rely + b
        v2f acc = vfma2(P[c * 10 + 0], relx, vsplat2(s));
#pragma unroll
        for (int i = 0; i < CIN; ++i)
            acc = vfma2(P[c * 10 + 2 + i], f[i], acc);
        h0[c] = vrelu2(acc);
    }

    // ---- layer 1: 8 -> 8, relu ----
    v2f h1[CH];
#pragma unroll
    for (int c = 0; c < CH; ++c) {
        v2f acc = vfma2(P[80 + c * 8], h0[0], vsplat2(P[160 + c]));
#pragma unroll
        for (int i = 1; i < CH; ++i)
            acc = vfma2(P[80 + c * 8 + i], h0[i], acc);
        h1[c] = vrelu2(acc);
    }

    // ---- layer 2: 8 -> 1 ----
    v2f o = vfma2(P[144], h1[0], vsplat2(P[168]));
#pragma unroll
    for (int i = 1; i < CH; ++i)
        o = vfma2(P[144 + i], h1[i], o);

    float2 ov; ov.x = o.x; ov.y = o.y;
    *reinterpret_cast<float2*>(out + (size_t)n * HW + p0) = ov;
}

extern "C" void kernel_launch(void* const* d_in, const int* in_sizes, int n_in,
                              void* d_out, int out_size, void* d_ws, size_t ws_size,
                              hipStream_t stream) {
    const float* feats   = (const float*)d_in[0];  // mask_feats [2,8,100,152]
    const float* params  = (const float*)d_in[1];  // mask_head_params [500,169]
    const float* locs    = (const float*)d_in[2];  // instance_locations [500,2]
    const float* soi     = (const float*)d_in[3];  // soi [500]
    const int*   im_inds = (const int*)d_in[4];    // im_inds [500]
    float*       out     = (float*)d_out;          // [500,1,100,152]

    const int pairs_per_inst = HW / PPT;                        // 7600
    dim3 block(256);
    dim3 grid((pairs_per_inst + block.x - 1) / block.x, NINST); // (30, 500)
    dyn_mask_head<<<grid, block, 0, stream>>>(feats, params, locs, soi, im_inds, out);
}

// Round 7
// 33.078 us; speedup vs baseline: 1.0894x; 1.0623x over previous
//
#include <hip/hip_runtime.h>
#include <stdint.h>

#define HGT 100
#define WID 152
#define HW (HGT * WID)          // 15200
#define NINST 500
#define CIN 8
#define CH 8
#define NPARAMS 169
#define PPT 4                    // pixels per thread (one float4)

// param layout per instance (169 floats):
//   w0: [0,80)   (8 x 10: wx, wy, f0..f7)
//   w1: [80,144) (8 x 8)   w2: [144,152) (1 x 8)
//   b0: [152,160) b1: [160,168) b2: [168]

typedef __fp16 h2 __attribute__((ext_vector_type(2)));  // matches builtin signatures

static __device__ __forceinline__ float dot2(h2 a, h2 b, float c) {
#if __has_builtin(__builtin_amdgcn_fdot2)
    return __builtin_amdgcn_fdot2(a, b, c, false);
#else
    float r = c;
    asm("v_dot2_f32_f16 %0, %1, %2, %0" : "+v"(r) : "v"(a), "v"(b));
    return r;
#endif
}

static __device__ __forceinline__ h2 pkrtz(float lo, float hi) {
    return __builtin_amdgcn_cvt_pkrtz(lo, hi);
}

static __device__ __forceinline__ h2 hrelu(h2 a) {
    h2 z = {(__fp16)0.0f, (__fp16)0.0f};
#if __has_builtin(__builtin_elementwise_max)
    return __builtin_elementwise_max(a, z);
#else
    h2 r;
    r.x = a.x > (__fp16)0.0f ? a.x : (__fp16)0.0f;
    r.y = a.y > (__fp16)0.0f ? a.y : (__fp16)0.0f;
    return r;
#endif
}

static __device__ __forceinline__ h2 bc(uint32_t u) {
    return __builtin_bit_cast(h2, u);
}

// LDS packed-weight layout (uint32 words, each = 2 x f16):
//   w0 feature pairs: word 4*c + j   (j=0..3) = (P[c*10+2+2j], P[c*10+3+2j])   [0,32)
//   w1 pairs:         word 32 + 4*c + j        = (P[80+8c+2j],  P[80+8c+2j+1])  [32,64)
//   w2 pairs:         word 64 + j              = (P[144+2j],    P[144+2j+1])    [64,68)

__global__ __launch_bounds__(256, 4) void dyn_mask_head(
    const float* __restrict__ feats,   // [2, 8, HW]
    const float* __restrict__ params,  // [500, 169]
    const float* __restrict__ locs,    // [500, 2]
    const float* __restrict__ soi,     // [500]
    const int*  __restrict__ im_inds,  // [500]
    float* __restrict__ out)           // [500, HW]
{
    __shared__ __align__(16) uint32_t wpk[68];

    const int n = blockIdx.y;                                   // instance
    const int t = threadIdx.x;
    const float* __restrict__ P = params + n * NPARAMS;

    // cooperative f32 -> f16x2 weight packing (68 words)
    if (t < 68) {
        int src;
        if (t < 32)      src = (t >> 2) * 10 + 2 + 2 * (t & 3); // w0 features
        else if (t < 64) src = 80 + 2 * (t - 32);               // w1
        else             src = 144 + 2 * (t - 64);              // w2
        wpk[t] = __builtin_bit_cast(uint32_t, pkrtz(P[src], P[src + 1]));
    }
    __syncthreads();

    const int q  = blockIdx.x * blockDim.x + t;                 // float4 index
    const int p0 = q * PPT;                                     // first pixel
    if (p0 < HW) {
        const int   im      = im_inds[n];
        const float lx      = locs[n * 2 + 0];
        const float ly      = locs[n * 2 + 1];
        const float inv_soi = 1.0f / soi[n];

        const int py  = p0 / WID;
        const int px0 = p0 - py * WID;
        const float rely = (ly - (float)(py * 8 + 4)) * inv_soi;    // f32, per-thread
        float relx[PPT];
#pragma unroll
        for (int r = 0; r < PPT; ++r)
            relx[r] = (lx - (float)((px0 + r) * 8 + 4)) * inv_soi;  // f32

        // features: 4 channel-pairs x 4 pixels, packed f16x2 (lo = even channel)
        h2 fpk[4][PPT];
        const float* fb = feats + (size_t)im * CIN * HW + p0;
#pragma unroll
        for (int m = 0; m < 4; ++m) {
            const float4 va = *reinterpret_cast<const float4*>(fb + (size_t)(2 * m) * HW);
            const float4 vb = *reinterpret_cast<const float4*>(fb + (size_t)(2 * m + 1) * HW);
            fpk[m][0] = pkrtz(va.x, vb.x);
            fpk[m][1] = pkrtz(va.y, vb.y);
            fpk[m][2] = pkrtz(va.z, vb.z);
            fpk[m][3] = pkrtz(va.w, vb.w);
        }

        // ---- layer 0: 10 -> 8, relu; coords in f32, features via dot2 ----
        h2 h0pk[4][PPT];                     // channel-pair m, pixel r
#pragma unroll
        for (int m = 0; m < 4; ++m) {
            const int c0 = 2 * m, c1 = 2 * m + 1;
            const uint4 wa = *reinterpret_cast<const uint4*>(&wpk[4 * c0]);
            const uint4 wb = *reinterpret_cast<const uint4*>(&wpk[4 * c1]);
            // coord part in f32 (|rel| can reach ~19; keep out of f16)
            const float sa = fmaf(P[c0 * 10 + 1], rely, P[152 + c0]);
            const float sb = fmaf(P[c1 * 10 + 1], rely, P[152 + c1]);
            float aa[PPT], ab[PPT];
#pragma unroll
            for (int r = 0; r < PPT; ++r) {
                float x = fmaf(P[c0 * 10 + 0], relx[r], sa);
                x = dot2(bc(wa.x), fpk[0][r], x);
                x = dot2(bc(wa.y), fpk[1][r], x);
                x = dot2(bc(wa.z), fpk[2][r], x);
                x = dot2(bc(wa.w), fpk[3][r], x);
                aa[r] = x;
                float y = fmaf(P[c1 * 10 + 0], relx[r], sb);
                y = dot2(bc(wb.x), fpk[0][r], y);
                y = dot2(bc(wb.y), fpk[1][r], y);
                y = dot2(bc(wb.z), fpk[2][r], y);
                y = dot2(bc(wb.w), fpk[3][r], y);
                ab[r] = y;
            }
#pragma unroll
            for (int r = 0; r < PPT; ++r)
                h0pk[m][r] = hrelu(pkrtz(aa[r], ab[r]));
        }

        // ---- layer 1: 8 -> 8, relu ----
        h2 h1pk[4][PPT];
#pragma unroll
        for (int m = 0; m < 4; ++m) {
            const int c0 = 2 * m, c1 = 2 * m + 1;
            const uint4 wa = *reinterpret_cast<const uint4*>(&wpk[32 + 4 * c0]);
            const uint4 wb = *reinterpret_cast<const uint4*>(&wpk[32 + 4 * c1]);
            const float ba = P[160 + c0];
            const float bb = P[160 + c1];
            float aa[PPT], ab[PPT];
#pragma unroll
            for (int r = 0; r < PPT; ++r) {
                float x = dot2(bc(wa.x), h0pk[0][r], ba);
                x = dot2(bc(wa.y), h0pk[1][r], x);
                x = dot2(bc(wa.z), h0pk[2][r], x);
                x = dot2(bc(wa.w), h0pk[3][r], x);
                aa[r] = x;
                float y = dot2(bc(wb.x), h0pk[0][r], bb);
                y = dot2(bc(wb.y), h0pk[1][r], y);
                y = dot2(bc(wb.z), h0pk[2][r], y);
                y = dot2(bc(wb.w), h0pk[3][r], y);
                ab[r] = y;
            }
#pragma unroll
            for (int r = 0; r < PPT; ++r)
                h1pk[m][r] = hrelu(pkrtz(aa[r], ab[r]));
        }

        // ---- layer 2: 8 -> 1 ----
        const uint4 w2 = *reinterpret_cast<const uint4*>(&wpk[64]);
        const float b2 = P[168];
        float o[PPT];
#pragma unroll
        for (int r = 0; r < PPT; ++r) {
            float x = dot2(bc(w2.x), h1pk[0][r], b2);
            x = dot2(bc(w2.y), h1pk[1][r], x);
            x = dot2(bc(w2.z), h1pk[2][r], x);
            x = dot2(bc(w2.w), h1pk[3][r], x);
            o[r] = x;
        }

        float4 ov;
        ov.x = o[0]; ov.y = o[1]; ov.z = o[2]; ov.w = o[3];
        *reinterpret_cast<float4*>(out + (size_t)n * HW + p0) = ov;
    }
}

extern "C" void kernel_launch(void* const* d_in, const int* in_sizes, int n_in,
                              void* d_out, int out_size, void* d_ws, size_t ws_size,
                              hipStream_t stream) {
    const float* feats   = (const float*)d_in[0];  // mask_feats [2,8,100,152]
    const float* params  = (const float*)d_in[1];  // mask_head_params [500,169]
    const float* locs    = (const float*)d_in[2];  // instance_locations [500,2]
    const float* soi     = (const float*)d_in[3];  // soi [500]
    const int*   im_inds = (const int*)d_in[4];    // im_inds [500]
    float*       out     = (float*)d_out;          // [500,1,100,152]

    const int quads_per_inst = HW / PPT;                        // 3800
    dim3 block(256);
    dim3 grid((quads_per_inst + block.x - 1) / block.x, NINST); // (15, 500)
    dyn_mask_head<<<grid, block, 0, stream>>>(feats, params, locs, soi, im_inds, out);
}